// Round 4
// baseline (2979.598 us; speedup 1.0000x reference)
//
#include <hip/hip_runtime.h>
#include <cstddef>

#define N_NODES_C 100000
#define N_EDGES_C 1600000
#define IN_CH_C 128
#define HID_CH_C 256
#define OUT_CH_C 128

// Bucket partition: 126 nodes per bucket, NB buckets.
#define NPB 126
#define NB 794            // ceil(100000/126)
#define DIV_MAGIC 34087043ULL  // ceil(2^32/126); exact for d < 2^32/122

typedef unsigned short u16;
typedef __attribute__((ext_vector_type(8))) short bf16x8;
typedef __attribute__((ext_vector_type(4))) float f32x4;

__device__ __forceinline__ u16 f2bf(float f) {
    unsigned u = __float_as_uint(f);
    u += 0x7fffu + ((u >> 16) & 1);  // round-to-nearest-even
    return (u16)(u >> 16);
}
__device__ __forceinline__ float bf2f(u16 b) {
    return __uint_as_float(((unsigned)b) << 16);
}
__device__ __forceinline__ unsigned bucket_of(int d) {
    return (unsigned)(((unsigned long long)(unsigned)d * DIV_MAGIC) >> 32);
}

// ---------------------------------------------------------------------------
// P1: per-bucket edge histogram (LDS hist per block -> global atomic add)
// ---------------------------------------------------------------------------

__global__ __launch_bounds__(1024) void p1_hist(const int* __restrict__ dst,
                                                int* __restrict__ bucket_counts) {
    __shared__ int hist[NB];
    int t = threadIdx.x;
    if (t < NB) hist[t] = 0;
    __syncthreads();
    int i = blockIdx.x * 1024 + t;  // int4 index; 4 edges/thread
    if (i * 4 < N_EDGES_C) {
        int4 d = ((const int4*)dst)[i];
        atomicAdd(&hist[bucket_of(d.x)], 1);
        atomicAdd(&hist[bucket_of(d.y)], 1);
        atomicAdd(&hist[bucket_of(d.z)], 1);
        atomicAdd(&hist[bucket_of(d.w)], 1);
    }
    __syncthreads();
    if (t < NB) {
        int c = hist[t];
        if (c) atomicAdd(&bucket_counts[t], c);
    }
}

// ---------------------------------------------------------------------------
// Scan bucket counts -> bucket_base (exclusive) + cursor init
// ---------------------------------------------------------------------------

__global__ __launch_bounds__(1024) void bucket_scan(const int* __restrict__ counts,
                                                    int* __restrict__ base,
                                                    int* __restrict__ cursor) {
    __shared__ int s[1024];
    int t = threadIdx.x;
    int v = (t < NB) ? counts[t] : 0;
    s[t] = v;
    __syncthreads();
    for (int off = 1; off < 1024; off <<= 1) {
        int u = (t >= off) ? s[t - off] : 0;
        __syncthreads();
        s[t] += u;
        __syncthreads();
    }
    if (t < NB) {
        int excl = s[t] - v;
        base[t] = excl;
        cursor[t] = excl;
    }
    if (t == NB - 1) base[NB] = s[t];
}

// ---------------------------------------------------------------------------
// P2: partition edges into bucket-grouped packed records.
// packed = (local_dst << 17) | src   (src < 2^17, local_dst < 126)
// Each block: LDS hist -> reserve contiguous per-bucket chunks via one global
// atomic per bucket -> rank via LDS cursors -> scatter (chunked, low write amp)
// 1024 threads x 16 edges = 16384 edges/block.
// ---------------------------------------------------------------------------

__global__ __launch_bounds__(1024) void p2_scatter(const int* __restrict__ src,
                                                   const int* __restrict__ dst,
                                                   int* __restrict__ cursor,
                                                   unsigned* __restrict__ edge_pkt) {
    __shared__ int hist[NB];
    __shared__ int lbase[NB];
    __shared__ int cur2[NB];
    int t = threadIdx.x;
    if (t < NB) { hist[t] = 0; cur2[t] = 0; }
    __syncthreads();

    int4 dd[4];
    int idx[4];
#pragma unroll
    for (int r = 0; r < 4; ++r) {
        int i = blockIdx.x * 4096 + r * 1024 + t;  // int4 index
        idx[r] = i;
        if (i * 4 < N_EDGES_C) {
            int4 d = ((const int4*)dst)[i];
            dd[r] = d;
            atomicAdd(&hist[bucket_of(d.x)], 1);
            atomicAdd(&hist[bucket_of(d.y)], 1);
            atomicAdd(&hist[bucket_of(d.z)], 1);
            atomicAdd(&hist[bucket_of(d.w)], 1);
        }
    }
    __syncthreads();
    if (t < NB) {
        int c = hist[t];
        if (c) lbase[t] = atomicAdd(&cursor[t], c);
    }
    __syncthreads();

#pragma unroll
    for (int r = 0; r < 4; ++r) {
        int i = idx[r];
        if (i * 4 < N_EDGES_C) {
            int4 s4 = ((const int4*)src)[i];
            int4 d = dd[r];
            {
                unsigned b = bucket_of(d.x);
                int local = d.x - (int)b * NPB;
                int pos = lbase[b] + atomicAdd(&cur2[b], 1);
                edge_pkt[pos] = ((unsigned)local << 17) | (unsigned)s4.x;
            }
            {
                unsigned b = bucket_of(d.y);
                int local = d.y - (int)b * NPB;
                int pos = lbase[b] + atomicAdd(&cur2[b], 1);
                edge_pkt[pos] = ((unsigned)local << 17) | (unsigned)s4.y;
            }
            {
                unsigned b = bucket_of(d.z);
                int local = d.z - (int)b * NPB;
                int pos = lbase[b] + atomicAdd(&cur2[b], 1);
                edge_pkt[pos] = ((unsigned)local << 17) | (unsigned)s4.z;
            }
            {
                unsigned b = bucket_of(d.w);
                int local = d.w - (int)b * NPB;
                int pos = lbase[b] + atomicAdd(&cur2[b], 1);
                edge_pkt[pos] = ((unsigned)local << 17) | (unsigned)s4.w;
            }
        }
    }
}

// ---------------------------------------------------------------------------
// fp32 -> bf16 converters
// ---------------------------------------------------------------------------

__global__ __launch_bounds__(256) void convert_f32_bf16(const float* __restrict__ in,
                                                        u16* __restrict__ out, int n4) {
    int i = blockIdx.x * 256 + threadIdx.x;
    if (i < n4) {
        float4 v = ((const float4*)in)[i];
        ushort4 o;
        o.x = f2bf(v.x); o.y = f2bf(v.y); o.z = f2bf(v.z); o.w = f2bf(v.w);
        ((ushort4*)out)[i] = o;
    }
}

// Transpose+convert all 4 weight matrices: W[K][N] fp32 -> WT[N][K] bf16.
__global__ __launch_bounds__(256) void convert_weights(
    const float* __restrict__ W1l, const float* __restrict__ W1r,
    const float* __restrict__ W2l, const float* __restrict__ W2r,
    u16* __restrict__ T1l, u16* __restrict__ T1r,
    u16* __restrict__ T2l, u16* __restrict__ T2r) {
    int id = blockIdx.x * 256 + threadIdx.x;  // 0 .. 131071
    int which = id >> 15;
    int r = id & 32767;
    if (which == 0) {        // [128][256] -> [256][128]
        int n = r >> 7, k = r & 127;
        T1l[r] = f2bf(W1l[k * 256 + n]);
    } else if (which == 1) {
        int n = r >> 7, k = r & 127;
        T1r[r] = f2bf(W1r[k * 256 + n]);
    } else if (which == 2) {  // [256][128] -> [128][256]
        int n = r >> 8, k = r & 255;
        T2l[r] = f2bf(W2l[k * 128 + n]);
    } else {
        int n = r >> 8, k = r & 255;
        T2r[r] = f2bf(W2r[k * 128 + n]);
    }
}

// ---------------------------------------------------------------------------
// Bucketed mean aggregation: one block per bucket (126 nodes x 128 ch fp32
// accumulator in LDS). 1024 threads = 16 waves; waves take 64-edge chunks,
// lane-load + shfl-broadcast indices, gather 4B/lane (256B/edge contiguous),
// ds_add_f32 accumulate. Epilogue: divide by degree, bf16-pack, write.
// LDS: 126*128*4 + 128*4 = 65024 B -> 2 blocks/CU (32 waves, full occupancy).
// ---------------------------------------------------------------------------

__global__ __launch_bounds__(1024) void agg_bucket(const u16* __restrict__ tbl,
                                                   const int* __restrict__ base,
                                                   const unsigned* __restrict__ edge_pkt,
                                                   u16* __restrict__ mean) {
    __shared__ float acc[NPB * 128];
    __shared__ int deg[128];
    const int t = threadIdx.x;
    const int wave = t >> 6;
    const int lane = t & 63;
    const int b = blockIdx.x;

    // zero acc + deg
#pragma unroll
    for (int r = 0; r < 4; ++r) {
        int i = r * 1024 + t;
        if (i < NPB * 32) ((float4*)acc)[i] = make_float4(0.f, 0.f, 0.f, 0.f);
    }
    if (t < 128) deg[t] = 0;
    __syncthreads();

    const int ebeg = base[b];
    const int ecnt = base[b + 1] - ebeg;

    for (int c0 = wave * 64; c0 < ecnt; c0 += 16 * 64) {
        int nn = ecnt - c0;
        if (nn > 64) nn = 64;
        unsigned pkt = 0;
        if (c0 + lane < ecnt) pkt = edge_pkt[ebeg + c0 + lane];
        int tt = 0;
        for (; tt + 4 <= nn; tt += 4) {
            unsigned p0 = __shfl(pkt, tt, 64);
            unsigned p1 = __shfl(pkt, tt + 1, 64);
            unsigned p2 = __shfl(pkt, tt + 2, 64);
            unsigned p3 = __shfl(pkt, tt + 3, 64);
            unsigned s0 = p0 & 0x1ffffu, l0 = p0 >> 17;
            unsigned s1 = p1 & 0x1ffffu, l1 = p1 >> 17;
            unsigned s2 = p2 & 0x1ffffu, l2 = p2 >> 17;
            unsigned s3 = p3 & 0x1ffffu, l3 = p3 >> 17;
            unsigned v0 = *(const unsigned*)(tbl + (size_t)s0 * 128 + lane * 2);
            unsigned v1 = *(const unsigned*)(tbl + (size_t)s1 * 128 + lane * 2);
            unsigned v2 = *(const unsigned*)(tbl + (size_t)s2 * 128 + lane * 2);
            unsigned v3 = *(const unsigned*)(tbl + (size_t)s3 * 128 + lane * 2);
            atomicAdd(&acc[l0 * 128 + lane * 2], __uint_as_float((v0 & 0xffffu) << 16));
            atomicAdd(&acc[l0 * 128 + lane * 2 + 1], __uint_as_float(v0 & 0xffff0000u));
            atomicAdd(&acc[l1 * 128 + lane * 2], __uint_as_float((v1 & 0xffffu) << 16));
            atomicAdd(&acc[l1 * 128 + lane * 2 + 1], __uint_as_float(v1 & 0xffff0000u));
            atomicAdd(&acc[l2 * 128 + lane * 2], __uint_as_float((v2 & 0xffffu) << 16));
            atomicAdd(&acc[l2 * 128 + lane * 2 + 1], __uint_as_float(v2 & 0xffff0000u));
            atomicAdd(&acc[l3 * 128 + lane * 2], __uint_as_float((v3 & 0xffffu) << 16));
            atomicAdd(&acc[l3 * 128 + lane * 2 + 1], __uint_as_float(v3 & 0xffff0000u));
            if (lane == 0) {
                atomicAdd(&deg[l0], 1);
                atomicAdd(&deg[l1], 1);
                atomicAdd(&deg[l2], 1);
                atomicAdd(&deg[l3], 1);
            }
        }
        for (; tt < nn; ++tt) {
            unsigned p = __shfl(pkt, tt, 64);
            unsigned s = p & 0x1ffffu, l = p >> 17;
            unsigned v = *(const unsigned*)(tbl + (size_t)s * 128 + lane * 2);
            atomicAdd(&acc[l * 128 + lane * 2], __uint_as_float((v & 0xffffu) << 16));
            atomicAdd(&acc[l * 128 + lane * 2 + 1], __uint_as_float(v & 0xffff0000u));
            if (lane == 0) atomicAdd(&deg[l], 1);
        }
    }
    __syncthreads();

    // epilogue: 16 waves x 8 nodes
#pragma unroll
    for (int r = 0; r < 8; ++r) {
        int n = wave * 8 + r;
        if (n < NPB) {
            int node = b * NPB + n;
            if (node < N_NODES_C) {
                int d = deg[n];
                float inv = d > 0 ? 1.f / (float)d : 0.f;
                float f0 = acc[n * 128 + lane * 2] * inv;
                float f1 = acc[n * 128 + lane * 2 + 1] * inv;
                unsigned o = (unsigned)f2bf(f0) | ((unsigned)f2bf(f1) << 16);
                *(unsigned*)(mean + (size_t)node * 128 + lane * 2) = o;
            }
        }
    }
}

// ---------------------------------------------------------------------------
// bf16 MFMA GEMM: OUT[M x NOUT] = act(A1@W1 [+ A2@W2] [+ resid] [+ bias])
// A: [M][K] bf16 row-major. WT: [NOUT][K] bf16 (pre-transposed).
// 128x128 block tile, 256 threads (4 waves, 2x2), BK=32, 16x16x32 MFMA.
// Staging via global_load_lds width=16. OOB tail rows read garbage that flows
// only into discarded output rows.
// ---------------------------------------------------------------------------

template <int K, int NOUT, bool DUAL, bool RELU, bool HAS_BIAS, bool RES, bool OUT_BF16>
__global__ __launch_bounds__(256) void gemm_mfma(const u16* __restrict__ A1,
                                                 const u16* __restrict__ W1T,
                                                 const u16* __restrict__ A2,
                                                 const u16* __restrict__ W2T,
                                                 const u16* __restrict__ resid,
                                                 const float* __restrict__ bias,
                                                 void* __restrict__ outv, int M) {
    alignas(16) __shared__ u16 As[128 * 32];
    alignas(16) __shared__ u16 Bs[128 * 32];

    const int tid = threadIdx.x;
    const int lane = tid & 63;
    const int wave = tid >> 6;
    const int qm = lane & 15;
    const int quad = lane >> 4;
    const int r0 = (wave >> 1) * 64;
    const int c0 = (wave & 1) * 64;
    const int m0 = blockIdx.x * 128;
    const int n0 = blockIdx.y * 128;

    f32x4 acc[4][4];
#pragma unroll
    for (int i = 0; i < 4; ++i)
#pragma unroll
        for (int j = 0; j < 4; ++j) acc[i][j] = (f32x4){0.f, 0.f, 0.f, 0.f};

    const int NMAT = DUAL ? 2 : 1;
#pragma unroll
    for (int mat = 0; mat < NMAT; ++mat) {
        const u16* __restrict__ A = mat ? A2 : A1;
        const u16* __restrict__ W = mat ? W2T : W1T;
#pragma unroll
        for (int k0 = 0; k0 < K; k0 += 32) {
#pragma unroll
            for (int it = 0; it < 2; ++it) {
                int c = it * 256 + tid;
                int row = c >> 2;
                int kc = c & 3;
                const u16* ga = A + (size_t)(m0 + row) * K + k0 + kc * 8;
                const u16* gb = W + (size_t)(n0 + row) * K + k0 + kc * 8;
                __builtin_amdgcn_global_load_lds(
                    (const __attribute__((address_space(1))) unsigned*)ga,
                    (__attribute__((address_space(3))) unsigned*)(As + c * 8), 16, 0, 0);
                __builtin_amdgcn_global_load_lds(
                    (const __attribute__((address_space(1))) unsigned*)gb,
                    (__attribute__((address_space(3))) unsigned*)(Bs + c * 8), 16, 0, 0);
            }
            __syncthreads();
            bf16x8 af[4], bfr[4];
#pragma unroll
            for (int i = 0; i < 4; ++i)
                af[i] = *(const bf16x8*)(As + (r0 + i * 16 + qm) * 32 + quad * 8);
#pragma unroll
            for (int j = 0; j < 4; ++j)
                bfr[j] = *(const bf16x8*)(Bs + (c0 + j * 16 + qm) * 32 + quad * 8);
#pragma unroll
            for (int i = 0; i < 4; ++i)
#pragma unroll
                for (int j = 0; j < 4; ++j)
                    acc[i][j] = __builtin_amdgcn_mfma_f32_16x16x32_bf16(
                        af[i], bfr[j], acc[i][j], 0, 0, 0);
            __syncthreads();
        }
    }

#pragma unroll
    for (int j = 0; j < 4; ++j) {
        int n = n0 + c0 + j * 16 + qm;
        float bv = HAS_BIAS ? bias[n] : 0.f;
#pragma unroll
        for (int i = 0; i < 4; ++i) {
            int rbase = m0 + r0 + i * 16 + quad * 4;
#pragma unroll
            for (int r = 0; r < 4; ++r) {
                int row = rbase + r;
                if (row < M) {
                    float val = acc[i][j][r] + bv;
                    if (RES) val += bf2f(resid[(size_t)row * NOUT + n]);
                    if (RELU) val = fmaxf(val, 0.f);
                    if (OUT_BF16)
                        ((u16*)outv)[(size_t)row * NOUT + n] = f2bf(val);
                    else
                        ((float*)outv)[(size_t)row * NOUT + n] = val;
                }
            }
        }
    }
}

// ---------------------------------------------------------------------------
// launch
// ---------------------------------------------------------------------------

extern "C" void kernel_launch(void* const* d_in, const int* in_sizes, int n_in,
                              void* d_out, int out_size, void* d_ws, size_t ws_size,
                              hipStream_t stream) {
    const float* x = (const float*)d_in[0];
    const int* ei = (const int*)d_in[1];
    const float* W1l = (const float*)d_in[2];
    const float* b1 = (const float*)d_in[3];
    const float* W1r = (const float*)d_in[4];
    const float* W2l = (const float*)d_in[5];
    const float* b2 = (const float*)d_in[6];
    const float* W2r = (const float*)d_in[7];
    float* out = (float*)d_out;

    const int* src = ei;
    const int* dst = ei + N_EDGES_C;

    // int workspace region (first 8 MiB)
    int* iw = (int*)d_ws;
    int* bucket_counts = iw;              // 1024
    int* bucket_base = iw + 1024;         // NB+1 -> pad 1024
    int* cursor = iw + 2048;              // 1024
    unsigned* edge_pkt = (unsigned*)(iw + 3072);  // 1.6M -> ends 1603072 ints
    u16* T1l = (u16*)(iw + 1603072);      // 4 x 32768 u16 = 256 KB
    u16* T1r = T1l + 32768;
    u16* T2l = T1r + 32768;
    u16* T2r = T2l + 32768;               // ends ~6.7 MB < 8 MiB
    // bf16 region at byte offset 8 MiB
    u16* ub = (u16*)((char*)d_ws + (8u << 20));
    u16* x_bf = ub;                       // 12.8M u16
    u16* h_bf = ub + 12800000;            // 25.6M
    u16* mean1 = ub + 38400000;           // 12.8M
    u16* p2 = ub + 51200000;              // 12.8M
    u16* mean2p = ub + 64000000;          // 12.8M

    hipMemsetAsync(bucket_counts, 0, 1024 * sizeof(int), stream);

    p1_hist<<<(N_EDGES_C / 4 + 1023) / 1024, 1024, 0, stream>>>(dst, bucket_counts);
    bucket_scan<<<1, 1024, 0, stream>>>(bucket_counts, bucket_base, cursor);
    p2_scatter<<<(N_EDGES_C / 4 + 4095) / 4096, 1024, 0, stream>>>(src, dst, cursor,
                                                                   edge_pkt);

    convert_f32_bf16<<<(3200000 + 255) / 256, 256, 0, stream>>>(x, x_bf, 3200000);
    convert_weights<<<512, 256, 0, stream>>>(W1l, W1r, W2l, W2r, T1l, T1r, T2l, T2r);

    // layer 1: mean1 = mean_{src->node} x   (128-ch bucketed gather)
    agg_bucket<<<NB, 1024, 0, stream>>>(x_bf, bucket_base, edge_pkt, mean1);
    // h = relu(mean1 @ W1_l + x @ W1_r + b1)
    {
        dim3 grid((N_NODES_C + 127) / 128, HID_CH_C / 128);
        gemm_mfma<IN_CH_C, HID_CH_C, true, true, true, false, true>
            <<<grid, 256, 0, stream>>>(mean1, T1l, x_bf, T1r, nullptr, b1, h_bf,
                                       N_NODES_C);
    }
    // p2 = h @ W2_l  (project 256 -> 128 BEFORE the gather)
    {
        dim3 grid((N_NODES_C + 127) / 128, OUT_CH_C / 128);
        gemm_mfma<HID_CH_C, OUT_CH_C, false, false, false, false, true>
            <<<grid, 256, 0, stream>>>(h_bf, T2l, nullptr, nullptr, nullptr, nullptr,
                                       p2, N_NODES_C);
    }
    // mean2p = mean_{src->node} p2
    agg_bucket<<<NB, 1024, 0, stream>>>(p2, bucket_base, edge_pkt, mean2p);
    // out = mean2p + h @ W2_r + b2
    {
        dim3 grid((N_NODES_C + 127) / 128, OUT_CH_C / 128);
        gemm_mfma<HID_CH_C, OUT_CH_C, false, false, true, true, false>
            <<<grid, 256, 0, stream>>>(h_bf, T2r, nullptr, nullptr, mean2p, b2, out,
                                       N_NODES_C);
    }
}

// Round 5
// 411.768 us; speedup vs baseline: 7.2361x; 7.2361x over previous
//
#include <hip/hip_runtime.h>
#include <cstddef>

#define N_NODES_C 100000
#define N_EDGES_C 1600000
#define IN_CH_C 128
#define HID_CH_C 256
#define OUT_CH_C 128

// Bucket partition: 126 nodes per bucket, NB buckets.
#define NPB 126
#define NB 794            // ceil(100000/126)
#define DIV_MAGIC 34087043ULL  // ceil(2^32/126); exact for d < 2^32/122
#define BCAP 2560         // max edges/bucket (mean 2015, sigma ~45 -> +12 sigma)

typedef unsigned short u16;
typedef __attribute__((ext_vector_type(8))) short bf16x8;
typedef __attribute__((ext_vector_type(4))) float f32x4;

__device__ __forceinline__ u16 f2bf(float f) {
    unsigned u = __float_as_uint(f);
    u += 0x7fffu + ((u >> 16) & 1);  // round-to-nearest-even
    return (u16)(u >> 16);
}
__device__ __forceinline__ float bf2f(u16 b) {
    return __uint_as_float(((unsigned)b) << 16);
}
__device__ __forceinline__ unsigned bucket_of(int d) {
    return (unsigned)(((unsigned long long)(unsigned)d * DIV_MAGIC) >> 32);
}

// ---------------------------------------------------------------------------
// P1: per-bucket edge histogram (LDS hist per block -> global atomic add)
// ---------------------------------------------------------------------------

__global__ __launch_bounds__(1024) void p1_hist(const int* __restrict__ dst,
                                                int* __restrict__ bucket_counts) {
    __shared__ int hist[NB];
    int t = threadIdx.x;
    if (t < NB) hist[t] = 0;
    __syncthreads();
    int i = blockIdx.x * 1024 + t;  // int4 index; 4 edges/thread
    if (i * 4 < N_EDGES_C) {
        int4 d = ((const int4*)dst)[i];
        atomicAdd(&hist[bucket_of(d.x)], 1);
        atomicAdd(&hist[bucket_of(d.y)], 1);
        atomicAdd(&hist[bucket_of(d.z)], 1);
        atomicAdd(&hist[bucket_of(d.w)], 1);
    }
    __syncthreads();
    if (t < NB) {
        int c = hist[t];
        if (c) atomicAdd(&bucket_counts[t], c);
    }
}

// ---------------------------------------------------------------------------
// Scan bucket counts -> bucket_base (exclusive) + cursor init
// ---------------------------------------------------------------------------

__global__ __launch_bounds__(1024) void bucket_scan(const int* __restrict__ counts,
                                                    int* __restrict__ base,
                                                    int* __restrict__ cursor) {
    __shared__ int s[1024];
    int t = threadIdx.x;
    int v = (t < NB) ? counts[t] : 0;
    s[t] = v;
    __syncthreads();
    for (int off = 1; off < 1024; off <<= 1) {
        int u = (t >= off) ? s[t - off] : 0;
        __syncthreads();
        s[t] += u;
        __syncthreads();
    }
    if (t < NB) {
        int excl = s[t] - v;
        base[t] = excl;
        cursor[t] = excl;
    }
    if (t == NB - 1) base[NB] = s[t];
}

// ---------------------------------------------------------------------------
// P2: partition edges into bucket-grouped packed records.
// packed = (local_dst << 17) | src   (src < 2^17, local_dst < 126)
// Per block: LDS hist -> one global atomic per bucket reserves a contiguous
// chunk -> rank via LDS int cursors -> chunked scatter (low write amp).
// ---------------------------------------------------------------------------

__global__ __launch_bounds__(1024) void p2_scatter(const int* __restrict__ src,
                                                   const int* __restrict__ dst,
                                                   int* __restrict__ cursor,
                                                   unsigned* __restrict__ edge_pkt) {
    __shared__ int hist[NB];
    __shared__ int lbase[NB];
    __shared__ int cur2[NB];
    int t = threadIdx.x;
    if (t < NB) { hist[t] = 0; cur2[t] = 0; }
    __syncthreads();

    int4 dd[4];
    int idx[4];
#pragma unroll
    for (int r = 0; r < 4; ++r) {
        int i = blockIdx.x * 4096 + r * 1024 + t;  // int4 index
        idx[r] = i;
        if (i * 4 < N_EDGES_C) {
            int4 d = ((const int4*)dst)[i];
            dd[r] = d;
            atomicAdd(&hist[bucket_of(d.x)], 1);
            atomicAdd(&hist[bucket_of(d.y)], 1);
            atomicAdd(&hist[bucket_of(d.z)], 1);
            atomicAdd(&hist[bucket_of(d.w)], 1);
        }
    }
    __syncthreads();
    if (t < NB) {
        int c = hist[t];
        if (c) lbase[t] = atomicAdd(&cursor[t], c);
    }
    __syncthreads();

#pragma unroll
    for (int r = 0; r < 4; ++r) {
        int i = idx[r];
        if (i * 4 < N_EDGES_C) {
            int4 s4 = ((const int4*)src)[i];
            int4 d = dd[r];
            {
                unsigned b = bucket_of(d.x);
                int local = d.x - (int)b * NPB;
                int pos = lbase[b] + atomicAdd(&cur2[b], 1);
                edge_pkt[pos] = ((unsigned)local << 17) | (unsigned)s4.x;
            }
            {
                unsigned b = bucket_of(d.y);
                int local = d.y - (int)b * NPB;
                int pos = lbase[b] + atomicAdd(&cur2[b], 1);
                edge_pkt[pos] = ((unsigned)local << 17) | (unsigned)s4.y;
            }
            {
                unsigned b = bucket_of(d.z);
                int local = d.z - (int)b * NPB;
                int pos = lbase[b] + atomicAdd(&cur2[b], 1);
                edge_pkt[pos] = ((unsigned)local << 17) | (unsigned)s4.z;
            }
            {
                unsigned b = bucket_of(d.w);
                int local = d.w - (int)b * NPB;
                int pos = lbase[b] + atomicAdd(&cur2[b], 1);
                edge_pkt[pos] = ((unsigned)local << 17) | (unsigned)s4.w;
            }
        }
    }
}

// ---------------------------------------------------------------------------
// fp32 -> bf16 converters
// ---------------------------------------------------------------------------

__global__ __launch_bounds__(256) void convert_f32_bf16(const float* __restrict__ in,
                                                        u16* __restrict__ out, int n4) {
    int i = blockIdx.x * 256 + threadIdx.x;
    if (i < n4) {
        float4 v = ((const float4*)in)[i];
        ushort4 o;
        o.x = f2bf(v.x); o.y = f2bf(v.y); o.z = f2bf(v.z); o.w = f2bf(v.w);
        ((ushort4*)out)[i] = o;
    }
}

// Transpose+convert all 4 weight matrices: W[K][N] fp32 -> WT[N][K] bf16.
__global__ __launch_bounds__(256) void convert_weights(
    const float* __restrict__ W1l, const float* __restrict__ W1r,
    const float* __restrict__ W2l, const float* __restrict__ W2r,
    u16* __restrict__ T1l, u16* __restrict__ T1r,
    u16* __restrict__ T2l, u16* __restrict__ T2r) {
    int id = blockIdx.x * 256 + threadIdx.x;  // 0 .. 131071
    int which = id >> 15;
    int r = id & 32767;
    if (which == 0) {        // [128][256] -> [256][128]
        int n = r >> 7, k = r & 127;
        T1l[r] = f2bf(W1l[k * 256 + n]);
    } else if (which == 1) {
        int n = r >> 7, k = r & 127;
        T1r[r] = f2bf(W1r[k * 256 + n]);
    } else if (which == 2) {  // [256][128] -> [128][256]
        int n = r >> 8, k = r & 255;
        T2l[r] = f2bf(W2l[k * 128 + n]);
    } else {
        int n = r >> 8, k = r & 255;
        T2r[r] = f2bf(W2r[k * 128 + n]);
    }
}

// ---------------------------------------------------------------------------
// Bucketed mean aggregation, register accumulate (NO fp LDS atomics):
// one block (512 thr = 8 waves) per bucket.
//   phase 1: LDS counting-sort of the bucket's packed edges by local_dst
//            (native integer ds_add atomics + 128-wide scan)
//   phase 2: wave-per-node gather: lane-batched index load from LDS, __shfl
//            broadcast, x4-unrolled 256B coalesced gathers, fp32 reg acc.
// Degree = LDS hist (free). LDS ~12.3 KB.
// ---------------------------------------------------------------------------

__global__ __launch_bounds__(512) void agg_bucket(const u16* __restrict__ tbl,
                                                  const int* __restrict__ base,
                                                  const unsigned* __restrict__ edge_pkt,
                                                  u16* __restrict__ mean) {
    __shared__ unsigned se[BCAP];   // src indices, grouped by local_dst
    __shared__ int lhist[128];
    __shared__ int lstart[128];
    __shared__ int lcur[128];
    __shared__ int stmp[128];

    const int t = threadIdx.x;
    const int wave = t >> 6;
    const int lane = t & 63;
    const int b = blockIdx.x;

    if (t < 128) lhist[t] = 0;
    __syncthreads();

    const int ebeg = base[b];
    int ecnt = base[b + 1] - ebeg;
    if (ecnt > BCAP) ecnt = BCAP;  // statistically unreachable guard

    // phase 1a: histogram by local_dst (native int LDS atomics)
    for (int i = t; i < ecnt; i += 512)
        atomicAdd(&lhist[edge_pkt[ebeg + i] >> 17], 1);
    __syncthreads();

    // phase 1b: exclusive scan of 128 counters
    if (t < 128) stmp[t] = lhist[t];
    __syncthreads();
    for (int off = 1; off < 128; off <<= 1) {
        int v = 0;
        if (t < 128 && t >= off) v = stmp[t - off];
        __syncthreads();
        if (t < 128) stmp[t] += v;
        __syncthreads();
    }
    if (t < 128) {
        int excl = stmp[t] - lhist[t];
        lstart[t] = excl;
        lcur[t] = excl;
    }
    __syncthreads();

    // phase 1c: rank + scatter into LDS (grouped by local_dst)
    for (int i = t; i < ecnt; i += 512) {
        unsigned p = edge_pkt[ebeg + i];  // L2-hot re-read
        int pos = atomicAdd(&lcur[p >> 17], 1);
        se[pos] = p & 0x1ffffu;
    }
    __syncthreads();

    // phase 2: wave-per-node gather, fp32 register accumulate (2 ch/lane)
    for (int n = wave; n < NPB; n += 8) {
        int node = b * NPB + n;
        if (node >= N_NODES_C) break;  // nodes ascend with n
        const int s0 = lstart[n];
        const int d = lhist[n];
        float ax = 0.f, ay = 0.f;
        for (int j0 = 0; j0 < d; j0 += 64) {
            int nn = d - j0;
            if (nn > 64) nn = 64;
            unsigned idx = 0;
            if (j0 + lane < d) idx = se[s0 + j0 + lane];
            int tt = 0;
            for (; tt + 4 <= nn; tt += 4) {
                unsigned s0i = __shfl(idx, tt, 64);
                unsigned s1i = __shfl(idx, tt + 1, 64);
                unsigned s2i = __shfl(idx, tt + 2, 64);
                unsigned s3i = __shfl(idx, tt + 3, 64);
                unsigned v0 = *(const unsigned*)(tbl + (size_t)s0i * 128 + lane * 2);
                unsigned v1 = *(const unsigned*)(tbl + (size_t)s1i * 128 + lane * 2);
                unsigned v2 = *(const unsigned*)(tbl + (size_t)s2i * 128 + lane * 2);
                unsigned v3 = *(const unsigned*)(tbl + (size_t)s3i * 128 + lane * 2);
                ax += __uint_as_float((v0 & 0xffffu) << 16);
                ay += __uint_as_float(v0 & 0xffff0000u);
                ax += __uint_as_float((v1 & 0xffffu) << 16);
                ay += __uint_as_float(v1 & 0xffff0000u);
                ax += __uint_as_float((v2 & 0xffffu) << 16);
                ay += __uint_as_float(v2 & 0xffff0000u);
                ax += __uint_as_float((v3 & 0xffffu) << 16);
                ay += __uint_as_float(v3 & 0xffff0000u);
            }
            for (; tt < nn; ++tt) {
                unsigned s = __shfl(idx, tt, 64);
                unsigned v = *(const unsigned*)(tbl + (size_t)s * 128 + lane * 2);
                ax += __uint_as_float((v & 0xffffu) << 16);
                ay += __uint_as_float(v & 0xffff0000u);
            }
        }
        float inv = d > 0 ? 1.f / (float)d : 0.f;
        unsigned o = (unsigned)f2bf(ax * inv) | ((unsigned)f2bf(ay * inv) << 16);
        *(unsigned*)(mean + (size_t)node * 128 + lane * 2) = o;
    }
}

// ---------------------------------------------------------------------------
// bf16 MFMA GEMM: OUT[M x NOUT] = act(A1@W1 [+ A2@W2] [+ resid] [+ bias])
// A: [M][K] bf16 row-major. WT: [NOUT][K] bf16 (pre-transposed).
// 128x128 block tile, 256 threads (4 waves, 2x2), BK=32, 16x16x32 MFMA.
// Staging via global_load_lds width=16. OOB tail rows read garbage that flows
// only into discarded output rows.
// ---------------------------------------------------------------------------

template <int K, int NOUT, bool DUAL, bool RELU, bool HAS_BIAS, bool RES, bool OUT_BF16>
__global__ __launch_bounds__(256) void gemm_mfma(const u16* __restrict__ A1,
                                                 const u16* __restrict__ W1T,
                                                 const u16* __restrict__ A2,
                                                 const u16* __restrict__ W2T,
                                                 const u16* __restrict__ resid,
                                                 const float* __restrict__ bias,
                                                 void* __restrict__ outv, int M) {
    alignas(16) __shared__ u16 As[128 * 32];
    alignas(16) __shared__ u16 Bs[128 * 32];

    const int tid = threadIdx.x;
    const int lane = tid & 63;
    const int wave = tid >> 6;
    const int qm = lane & 15;
    const int quad = lane >> 4;
    const int r0 = (wave >> 1) * 64;
    const int c0 = (wave & 1) * 64;
    const int m0 = blockIdx.x * 128;
    const int n0 = blockIdx.y * 128;

    f32x4 acc[4][4];
#pragma unroll
    for (int i = 0; i < 4; ++i)
#pragma unroll
        for (int j = 0; j < 4; ++j) acc[i][j] = (f32x4){0.f, 0.f, 0.f, 0.f};

    const int NMAT = DUAL ? 2 : 1;
#pragma unroll
    for (int mat = 0; mat < NMAT; ++mat) {
        const u16* __restrict__ A = mat ? A2 : A1;
        const u16* __restrict__ W = mat ? W2T : W1T;
#pragma unroll
        for (int k0 = 0; k0 < K; k0 += 32) {
#pragma unroll
            for (int it = 0; it < 2; ++it) {
                int c = it * 256 + tid;
                int row = c >> 2;
                int kc = c & 3;
                const u16* ga = A + (size_t)(m0 + row) * K + k0 + kc * 8;
                const u16* gb = W + (size_t)(n0 + row) * K + k0 + kc * 8;
                __builtin_amdgcn_global_load_lds(
                    (const __attribute__((address_space(1))) unsigned*)ga,
                    (__attribute__((address_space(3))) unsigned*)(As + c * 8), 16, 0, 0);
                __builtin_amdgcn_global_load_lds(
                    (const __attribute__((address_space(1))) unsigned*)gb,
                    (__attribute__((address_space(3))) unsigned*)(Bs + c * 8), 16, 0, 0);
            }
            __syncthreads();
            bf16x8 af[4], bfr[4];
#pragma unroll
            for (int i = 0; i < 4; ++i)
                af[i] = *(const bf16x8*)(As + (r0 + i * 16 + qm) * 32 + quad * 8);
#pragma unroll
            for (int j = 0; j < 4; ++j)
                bfr[j] = *(const bf16x8*)(Bs + (c0 + j * 16 + qm) * 32 + quad * 8);
#pragma unroll
            for (int i = 0; i < 4; ++i)
#pragma unroll
                for (int j = 0; j < 4; ++j)
                    acc[i][j] = __builtin_amdgcn_mfma_f32_16x16x32_bf16(
                        af[i], bfr[j], acc[i][j], 0, 0, 0);
            __syncthreads();
        }
    }

#pragma unroll
    for (int j = 0; j < 4; ++j) {
        int n = n0 + c0 + j * 16 + qm;
        float bv = HAS_BIAS ? bias[n] : 0.f;
#pragma unroll
        for (int i = 0; i < 4; ++i) {
            int rbase = m0 + r0 + i * 16 + quad * 4;
#pragma unroll
            for (int r = 0; r < 4; ++r) {
                int row = rbase + r;
                if (row < M) {
                    float val = acc[i][j][r] + bv;
                    if (RES) val += bf2f(resid[(size_t)row * NOUT + n]);
                    if (RELU) val = fmaxf(val, 0.f);
                    if (OUT_BF16)
                        ((u16*)outv)[(size_t)row * NOUT + n] = f2bf(val);
                    else
                        ((float*)outv)[(size_t)row * NOUT + n] = val;
                }
            }
        }
    }
}

// ---------------------------------------------------------------------------
// launch
// ---------------------------------------------------------------------------

extern "C" void kernel_launch(void* const* d_in, const int* in_sizes, int n_in,
                              void* d_out, int out_size, void* d_ws, size_t ws_size,
                              hipStream_t stream) {
    const float* x = (const float*)d_in[0];
    const int* ei = (const int*)d_in[1];
    const float* W1l = (const float*)d_in[2];
    const float* b1 = (const float*)d_in[3];
    const float* W1r = (const float*)d_in[4];
    const float* W2l = (const float*)d_in[5];
    const float* b2 = (const float*)d_in[6];
    const float* W2r = (const float*)d_in[7];
    float* out = (float*)d_out;

    const int* src = ei;
    const int* dst = ei + N_EDGES_C;

    // int workspace region (first 8 MiB)
    int* iw = (int*)d_ws;
    int* bucket_counts = iw;              // 1024
    int* bucket_base = iw + 1024;         // NB+1 -> pad 1024
    int* cursor = iw + 2048;              // 1024
    unsigned* edge_pkt = (unsigned*)(iw + 3072);  // 1.6M -> ends 1603072 ints
    u16* T1l = (u16*)(iw + 1603072);      // 4 x 32768 u16 = 256 KB
    u16* T1r = T1l + 32768;
    u16* T2l = T1r + 32768;
    u16* T2r = T2l + 32768;               // ends ~6.7 MB < 8 MiB
    // bf16 region at byte offset 8 MiB
    u16* ub = (u16*)((char*)d_ws + (8u << 20));
    u16* x_bf = ub;                       // 12.8M u16
    u16* h_bf = ub + 12800000;            // 25.6M
    u16* mean1 = ub + 38400000;           // 12.8M
    u16* p2 = ub + 51200000;              // 12.8M
    u16* mean2p = ub + 64000000;          // 12.8M

    hipMemsetAsync(bucket_counts, 0, 1024 * sizeof(int), stream);

    p1_hist<<<(N_EDGES_C / 4 + 1023) / 1024, 1024, 0, stream>>>(dst, bucket_counts);
    bucket_scan<<<1, 1024, 0, stream>>>(bucket_counts, bucket_base, cursor);
    p2_scatter<<<(N_EDGES_C / 4 + 4095) / 4096, 1024, 0, stream>>>(src, dst, cursor,
                                                                   edge_pkt);

    convert_f32_bf16<<<(3200000 + 255) / 256, 256, 0, stream>>>(x, x_bf, 3200000);
    convert_weights<<<512, 256, 0, stream>>>(W1l, W1r, W2l, W2r, T1l, T1r, T2l, T2r);

    // layer 1: mean1 = mean_{src->node} x   (128-ch bucketed gather)
    agg_bucket<<<NB, 512, 0, stream>>>(x_bf, bucket_base, edge_pkt, mean1);
    // h = relu(mean1 @ W1_l + x @ W1_r + b1)
    {
        dim3 grid((N_NODES_C + 127) / 128, HID_CH_C / 128);
        gemm_mfma<IN_CH_C, HID_CH_C, true, true, true, false, true>
            <<<grid, 256, 0, stream>>>(mean1, T1l, x_bf, T1r, nullptr, b1, h_bf,
                                       N_NODES_C);
    }
    // p2 = h @ W2_l  (project 256 -> 128 BEFORE the gather)
    {
        dim3 grid((N_NODES_C + 127) / 128, OUT_CH_C / 128);
        gemm_mfma<HID_CH_C, OUT_CH_C, false, false, false, false, true>
            <<<grid, 256, 0, stream>>>(h_bf, T2l, nullptr, nullptr, nullptr, nullptr,
                                       p2, N_NODES_C);
    }
    // mean2p = mean_{src->node} p2
    agg_bucket<<<NB, 512, 0, stream>>>(p2, bucket_base, edge_pkt, mean2p);
    // out = mean2p + h @ W2_r + b2
    {
        dim3 grid((N_NODES_C + 127) / 128, OUT_CH_C / 128);
        gemm_mfma<HID_CH_C, OUT_CH_C, false, false, true, true, false>
            <<<grid, 256, 0, stream>>>(h_bf, T2r, nullptr, nullptr, mean2p, b2, out,
                                       N_NODES_C);
    }
}

// Round 6
// 399.060 us; speedup vs baseline: 7.4665x; 1.0318x over previous
//
#include <hip/hip_runtime.h>
#include <cstddef>

#define N_NODES_C 100000
#define N_EDGES_C 1600000

// Bucket partition: 126 nodes per bucket, NB buckets.
#define NPB 126
#define NB 794            // ceil(100000/126)
#define DIV_MAGIC 34087043ULL  // ceil(2^32/126); exact for d < 2^32/122
#define BCAP 2560         // max edges/bucket (mean 2015, +12 sigma)

#define CONV_BLOCKS 12500  // 3.2M float4 / 256
#define WB_BLOCKS 512      // weight transpose blocks
#define P1_BLOCKS 1563     // 400128 int4 slots / 256

typedef unsigned short u16;
typedef __attribute__((ext_vector_type(8))) short bf16x8;
typedef __attribute__((ext_vector_type(4))) float f32x4;

__device__ __forceinline__ u16 f2bf(float f) {
    unsigned u = __float_as_uint(f);
    u += 0x7fffu + ((u >> 16) & 1);  // round-to-nearest-even
    return (u16)(u >> 16);
}
__device__ __forceinline__ float bf2f(u16 b) {
    return __uint_as_float(((unsigned)b) << 16);
}
__device__ __forceinline__ unsigned bucket_of(int d) {
    return (unsigned)(((unsigned long long)(unsigned)d * DIV_MAGIC) >> 32);
}

// ---------------------------------------------------------------------------
// Front fused: x fp32->bf16 convert | weight transpose+convert | P1 histogram
// ---------------------------------------------------------------------------

__global__ __launch_bounds__(256) void front_fused(
    const float* __restrict__ x, const int* __restrict__ dst,
    const float* __restrict__ W1l, const float* __restrict__ W1r,
    const float* __restrict__ W2l, const float* __restrict__ W2r,
    u16* __restrict__ x_bf, u16* __restrict__ T1l, u16* __restrict__ T1r,
    u16* __restrict__ T2l, u16* __restrict__ T2r,
    int* __restrict__ bucket_counts) {
    const int b = blockIdx.x;
    const int t = threadIdx.x;
    if (b < CONV_BLOCKS) {
        int i = b * 256 + t;
        if (i < 3200000) {
            float4 v = ((const float4*)x)[i];
            ushort4 o;
            o.x = f2bf(v.x); o.y = f2bf(v.y); o.z = f2bf(v.z); o.w = f2bf(v.w);
            ((ushort4*)x_bf)[i] = o;
        }
    } else if (b < CONV_BLOCKS + WB_BLOCKS) {
        int id = (b - CONV_BLOCKS) * 256 + t;  // 0..131071
        int which = id >> 15;
        int r = id & 32767;
        if (which == 0) {        // [128][256] -> [256][128]
            int n = r >> 7, k = r & 127;
            T1l[r] = f2bf(W1l[k * 256 + n]);
        } else if (which == 1) {
            int n = r >> 7, k = r & 127;
            T1r[r] = f2bf(W1r[k * 256 + n]);
        } else if (which == 2) {  // [256][128] -> [128][256]
            int n = r >> 8, k = r & 255;
            T2l[r] = f2bf(W2l[k * 128 + n]);
        } else {
            int n = r >> 8, k = r & 255;
            T2r[r] = f2bf(W2r[k * 128 + n]);
        }
    } else {
        __shared__ int hist[NB];
        for (int j = t; j < NB; j += 256) hist[j] = 0;
        __syncthreads();
        int i = (b - CONV_BLOCKS - WB_BLOCKS) * 256 + t;  // int4 index
        if (i * 4 < N_EDGES_C) {
            int4 d = ((const int4*)dst)[i];
            atomicAdd(&hist[bucket_of(d.x)], 1);
            atomicAdd(&hist[bucket_of(d.y)], 1);
            atomicAdd(&hist[bucket_of(d.z)], 1);
            atomicAdd(&hist[bucket_of(d.w)], 1);
        }
        __syncthreads();
        for (int j = t; j < NB; j += 256) {
            int c = hist[j];
            if (c) atomicAdd(&bucket_counts[j], c);
        }
    }
}

// ---------------------------------------------------------------------------
// Scan bucket counts -> bucket_base (exclusive) + cursor init
// ---------------------------------------------------------------------------

__global__ __launch_bounds__(1024) void bucket_scan(const int* __restrict__ counts,
                                                    int* __restrict__ base,
                                                    int* __restrict__ cursor) {
    __shared__ int s[1024];
    int t = threadIdx.x;
    int v = (t < NB) ? counts[t] : 0;
    s[t] = v;
    __syncthreads();
    for (int off = 1; off < 1024; off <<= 1) {
        int u = (t >= off) ? s[t - off] : 0;
        __syncthreads();
        s[t] += u;
        __syncthreads();
    }
    if (t < NB) {
        int excl = s[t] - v;
        base[t] = excl;
        cursor[t] = excl;
    }
    if (t == NB - 1) base[NB] = s[t];
}

// ---------------------------------------------------------------------------
// P2: partition edges into bucket-grouped packed records.
// packed = (local_dst << 17) | src
// ---------------------------------------------------------------------------

__global__ __launch_bounds__(1024) void p2_scatter(const int* __restrict__ src,
                                                   const int* __restrict__ dst,
                                                   int* __restrict__ cursor,
                                                   unsigned* __restrict__ edge_pkt) {
    __shared__ int hist[NB];
    __shared__ int lbase[NB];
    __shared__ int cur2[NB];
    int t = threadIdx.x;
    if (t < NB) { hist[t] = 0; cur2[t] = 0; }
    __syncthreads();

    int4 dd[4];
    int idx[4];
#pragma unroll
    for (int r = 0; r < 4; ++r) {
        int i = blockIdx.x * 4096 + r * 1024 + t;  // int4 index
        idx[r] = i;
        if (i * 4 < N_EDGES_C) {
            int4 d = ((const int4*)dst)[i];
            dd[r] = d;
            atomicAdd(&hist[bucket_of(d.x)], 1);
            atomicAdd(&hist[bucket_of(d.y)], 1);
            atomicAdd(&hist[bucket_of(d.z)], 1);
            atomicAdd(&hist[bucket_of(d.w)], 1);
        }
    }
    __syncthreads();
    if (t < NB) {
        int c = hist[t];
        if (c) lbase[t] = atomicAdd(&cursor[t], c);
    }
    __syncthreads();

#pragma unroll
    for (int r = 0; r < 4; ++r) {
        int i = idx[r];
        if (i * 4 < N_EDGES_C) {
            int4 s4 = ((const int4*)src)[i];
            int4 d = dd[r];
            {
                unsigned b = bucket_of(d.x);
                int local = d.x - (int)b * NPB;
                int pos = lbase[b] + atomicAdd(&cur2[b], 1);
                edge_pkt[pos] = ((unsigned)local << 17) | (unsigned)s4.x;
            }
            {
                unsigned b = bucket_of(d.y);
                int local = d.y - (int)b * NPB;
                int pos = lbase[b] + atomicAdd(&cur2[b], 1);
                edge_pkt[pos] = ((unsigned)local << 17) | (unsigned)s4.y;
            }
            {
                unsigned b = bucket_of(d.z);
                int local = d.z - (int)b * NPB;
                int pos = lbase[b] + atomicAdd(&cur2[b], 1);
                edge_pkt[pos] = ((unsigned)local << 17) | (unsigned)s4.z;
            }
            {
                unsigned b = bucket_of(d.w);
                int local = d.w - (int)b * NPB;
                int pos = lbase[b] + atomicAdd(&cur2[b], 1);
                edge_pkt[pos] = ((unsigned)local << 17) | (unsigned)s4.w;
            }
        }
    }
}

// ---------------------------------------------------------------------------
// Bucketed mean aggregation (round-5 structure, proven 65 us):
// phase 1: LDS int counting-sort by local_dst; phase 2: wave-per-node gather,
// fp32 register accumulate.
// FINAL=false: write bf16 mean.  FINAL=true: write fp32 out = mean + resid.
// ---------------------------------------------------------------------------

template <bool FINAL>
__global__ __launch_bounds__(512) void agg_bucket(const u16* __restrict__ tbl,
                                                  const int* __restrict__ base,
                                                  const unsigned* __restrict__ edge_pkt,
                                                  const u16* __restrict__ resid,
                                                  void* __restrict__ outv) {
    __shared__ unsigned se[BCAP];
    __shared__ int lhist[128];
    __shared__ int lstart[128];
    __shared__ int lcur[128];
    __shared__ int stmp[128];

    const int t = threadIdx.x;
    const int wave = t >> 6;
    const int lane = t & 63;
    const int b = blockIdx.x;

    if (t < 128) lhist[t] = 0;
    __syncthreads();

    const int ebeg = base[b];
    int ecnt = base[b + 1] - ebeg;
    if (ecnt > BCAP) ecnt = BCAP;

    for (int i = t; i < ecnt; i += 512)
        atomicAdd(&lhist[edge_pkt[ebeg + i] >> 17], 1);
    __syncthreads();

    if (t < 128) stmp[t] = lhist[t];
    __syncthreads();
    for (int off = 1; off < 128; off <<= 1) {
        int v = 0;
        if (t < 128 && t >= off) v = stmp[t - off];
        __syncthreads();
        if (t < 128) stmp[t] += v;
        __syncthreads();
    }
    if (t < 128) {
        int excl = stmp[t] - lhist[t];
        lstart[t] = excl;
        lcur[t] = excl;
    }
    __syncthreads();

    for (int i = t; i < ecnt; i += 512) {
        unsigned p = edge_pkt[ebeg + i];
        int pos = atomicAdd(&lcur[p >> 17], 1);
        se[pos] = p & 0x1ffffu;
    }
    __syncthreads();

    for (int n = wave; n < NPB; n += 8) {
        int node = b * NPB + n;
        if (node >= N_NODES_C) break;
        const int s0 = lstart[n];
        const int d = lhist[n];
        float ax = 0.f, ay = 0.f;
        for (int j0 = 0; j0 < d; j0 += 64) {
            int nn = d - j0;
            if (nn > 64) nn = 64;
            unsigned idx = 0;
            if (j0 + lane < d) idx = se[s0 + j0 + lane];
            int tt = 0;
            for (; tt + 4 <= nn; tt += 4) {
                unsigned s0i = __shfl(idx, tt, 64);
                unsigned s1i = __shfl(idx, tt + 1, 64);
                unsigned s2i = __shfl(idx, tt + 2, 64);
                unsigned s3i = __shfl(idx, tt + 3, 64);
                unsigned v0 = *(const unsigned*)(tbl + (size_t)s0i * 128 + lane * 2);
                unsigned v1 = *(const unsigned*)(tbl + (size_t)s1i * 128 + lane * 2);
                unsigned v2 = *(const unsigned*)(tbl + (size_t)s2i * 128 + lane * 2);
                unsigned v3 = *(const unsigned*)(tbl + (size_t)s3i * 128 + lane * 2);
                ax += __uint_as_float((v0 & 0xffffu) << 16);
                ay += __uint_as_float(v0 & 0xffff0000u);
                ax += __uint_as_float((v1 & 0xffffu) << 16);
                ay += __uint_as_float(v1 & 0xffff0000u);
                ax += __uint_as_float((v2 & 0xffffu) << 16);
                ay += __uint_as_float(v2 & 0xffff0000u);
                ax += __uint_as_float((v3 & 0xffffu) << 16);
                ay += __uint_as_float(v3 & 0xffff0000u);
            }
            for (; tt < nn; ++tt) {
                unsigned s = __shfl(idx, tt, 64);
                unsigned v = *(const unsigned*)(tbl + (size_t)s * 128 + lane * 2);
                ax += __uint_as_float((v & 0xffffu) << 16);
                ay += __uint_as_float(v & 0xffff0000u);
            }
        }
        float inv = d > 0 ? 1.f / (float)d : 0.f;
        if (FINAL) {
            unsigned rp = *(const unsigned*)(resid + (size_t)node * 128 + lane * 2);
            float2 o;
            o.x = ax * inv + __uint_as_float((rp & 0xffffu) << 16);
            o.y = ay * inv + __uint_as_float(rp & 0xffff0000u);
            *(float2*)((float*)outv + (size_t)node * 128 + lane * 2) = o;
        } else {
            unsigned o = (unsigned)f2bf(ax * inv) | ((unsigned)f2bf(ay * inv) << 16);
            *(unsigned*)((u16*)outv + (size_t)node * 128 + lane * 2) = o;
        }
    }
}

// ---------------------------------------------------------------------------
// Mega-fused GEMM: per 64-row M-tile,
//   phase A: h = relu(mean1@W1l + x@W1r + b1)  [64 x 256] -> LDS (A-frag order)
//   phase B: p2 = h@W2l (bf16), outp = h@W2r + b2 (bf16)
// h never touches HBM. 256 thr = 4 waves (2x2).
// Fragment layouts (HW-verified): A: lane=m, k=quad*8+j; B from WT[n][k];
// C/D: col=lane&15, row=quad*4+reg.
// LDS: hfrag 32 KB + As 4 KB + Bs 16 KB = 52 KB -> 3 blocks/CU.
// ---------------------------------------------------------------------------

__global__ __launch_bounds__(256) void fused_l1l2(
    const u16* __restrict__ A1 /*mean1*/, const u16* __restrict__ A2 /*x_bf*/,
    const u16* __restrict__ T1l, const u16* __restrict__ T1r,   // [256][128]
    const u16* __restrict__ T2l, const u16* __restrict__ T2r,   // [128][256]
    const float* __restrict__ b1, const float* __restrict__ b2,
    u16* __restrict__ p2, u16* __restrict__ outp, int M) {
    alignas(16) __shared__ u16 hfrag[64 * 256];  // 32 KB, fragment-order
    alignas(16) __shared__ u16 As[64 * 32];      // 4 KB
    alignas(16) __shared__ u16 Bs[256 * 32];     // 16 KB (A: W1 tile; B: W2l|W2r)

    const int tid = threadIdx.x;
    const int lane = tid & 63;
    const int wave = tid >> 6;
    const int qm = lane & 15;
    const int quad = lane >> 4;
    const int m0 = blockIdx.x * 64;

    // ---------------- phase A: h tile ----------------
    const int wr0 = (wave >> 1) * 32;   // rows 0/32
    const int wc0 = (wave & 1) * 128;   // cols 0/128
    f32x4 acch[2][8];
#pragma unroll
    for (int i = 0; i < 2; ++i)
#pragma unroll
        for (int j = 0; j < 8; ++j) acch[i][j] = (f32x4){0.f, 0.f, 0.f, 0.f};

#pragma unroll
    for (int mat = 0; mat < 2; ++mat) {
        const u16* __restrict__ A = mat ? A2 : A1;
        const u16* __restrict__ W = mat ? T1r : T1l;
#pragma unroll
        for (int k0 = 0; k0 < 128; k0 += 32) {
            // As: 64x32 (256 chunks, 1/thread); Bs: 256x32 (1024 chunks, 4/thread)
            {
                int c = tid;
                int row = c >> 2, kc = c & 3;
                __builtin_amdgcn_global_load_lds(
                    (const __attribute__((address_space(1))) unsigned*)(
                        A + (size_t)(m0 + row) * 128 + k0 + kc * 8),
                    (__attribute__((address_space(3))) unsigned*)(As + c * 8), 16, 0, 0);
            }
#pragma unroll
            for (int r = 0; r < 4; ++r) {
                int c = r * 256 + tid;
                int row = c >> 2, kc = c & 3;
                __builtin_amdgcn_global_load_lds(
                    (const __attribute__((address_space(1))) unsigned*)(
                        W + (size_t)row * 128 + k0 + kc * 8),
                    (__attribute__((address_space(3))) unsigned*)(Bs + c * 8), 16, 0, 0);
            }
            __syncthreads();
            bf16x8 af[2], bf[8];
#pragma unroll
            for (int i = 0; i < 2; ++i)
                af[i] = *(const bf16x8*)(As + (wr0 + i * 16 + qm) * 32 + quad * 8);
#pragma unroll
            for (int j = 0; j < 8; ++j)
                bf[j] = *(const bf16x8*)(Bs + (wc0 + j * 16 + qm) * 32 + quad * 8);
#pragma unroll
            for (int i = 0; i < 2; ++i)
#pragma unroll
                for (int j = 0; j < 8; ++j)
                    acch[i][j] = __builtin_amdgcn_mfma_f32_16x16x32_bf16(
                        af[i], bf[j], acch[i][j], 0, 0, 0);
            __syncthreads();
        }
    }

    // epilogue A: +b1, relu, write to hfrag in A-fragment order:
    // addr(m', n) = ((ks*4 + (m'>>4))*16 + (m'&15))*32 + quadB*8 + jB
    //   with ks=n>>5, quadB=(n>>3)&3, jB=n&7
#pragma unroll
    for (int j = 0; j < 8; ++j) {
        int n = wc0 + j * 16 + qm;
        float bb = b1[n];
        int ks = n >> 5, quadB = (n >> 3) & 3, jB = n & 7;
#pragma unroll
        for (int i = 0; i < 2; ++i) {
#pragma unroll
            for (int r = 0; r < 4; ++r) {
                int mloc = wr0 + i * 16 + quad * 4 + r;
                float v = fmaxf(acch[i][j][r] + bb, 0.f);
                hfrag[((ks * 4 + (mloc >> 4)) * 16 + (mloc & 15)) * 32 + quadB * 8 + jB] =
                    f2bf(v);
            }
        }
    }
    __syncthreads();

    // ---------------- phase B: p2 / outp ----------------
    const int wrB = (wave >> 1) * 32;   // rows 0/32
    const int wcB = (wave & 1) * 64;    // cols 0/64 (of 128)
    f32x4 accp[2][4], acco[2][4];
#pragma unroll
    for (int i = 0; i < 2; ++i)
#pragma unroll
        for (int j = 0; j < 4; ++j) {
            accp[i][j] = (f32x4){0.f, 0.f, 0.f, 0.f};
            acco[i][j] = (f32x4){0.f, 0.f, 0.f, 0.f};
        }

#pragma unroll
    for (int ks = 0; ks < 8; ++ks) {
        // stage W2l|W2r k-chunk: Bs[mat][128][32], 1024 chunks, 4/thread
#pragma unroll
        for (int r = 0; r < 4; ++r) {
            int c = r * 256 + tid;
            int matc = c >> 9;
            int row = (c >> 2) & 127;
            int kc = c & 3;
            const u16* W = matc ? T2r : T2l;
            __builtin_amdgcn_global_load_lds(
                (const __attribute__((address_space(1))) unsigned*)(
                    W + (size_t)row * 256 + ks * 32 + kc * 8),
                (__attribute__((address_space(3))) unsigned*)(Bs + c * 8), 16, 0, 0);
        }
        __syncthreads();
        bf16x8 af[2], bfl[4], bfr[4];
#pragma unroll
        for (int i = 0; i < 2; ++i)
            af[i] = *(const bf16x8*)(hfrag +
                                     ((ks * 4 + (wrB >> 4) + i) * 16 + qm) * 32 + quad * 8);
#pragma unroll
        for (int j = 0; j < 4; ++j) {
            bfl[j] = *(const bf16x8*)(Bs + (wcB + j * 16 + qm) * 32 + quad * 8);
            bfr[j] = *(const bf16x8*)(Bs + 4096 + (wcB + j * 16 + qm) * 32 + quad * 8);
        }
#pragma unroll
        for (int i = 0; i < 2; ++i)
#pragma unroll
            for (int j = 0; j < 4; ++j) {
                accp[i][j] = __builtin_amdgcn_mfma_f32_16x16x32_bf16(af[i], bfl[j],
                                                                    accp[i][j], 0, 0, 0);
                acco[i][j] = __builtin_amdgcn_mfma_f32_16x16x32_bf16(af[i], bfr[j],
                                                                    acco[i][j], 0, 0, 0);
            }
        __syncthreads();
    }

    // epilogue B
#pragma unroll
    for (int j = 0; j < 4; ++j) {
        int n = wcB + j * 16 + qm;
        float bb2 = b2[n];
#pragma unroll
        for (int i = 0; i < 2; ++i) {
#pragma unroll
            for (int r = 0; r < 4; ++r) {
                int row = m0 + wrB + i * 16 + quad * 4 + r;
                if (row < M) {
                    p2[(size_t)row * 128 + n] = f2bf(accp[i][j][r]);
                    outp[(size_t)row * 128 + n] = f2bf(acco[i][j][r] + bb2);
                }
            }
        }
    }
}

// ---------------------------------------------------------------------------
// launch
// ---------------------------------------------------------------------------

extern "C" void kernel_launch(void* const* d_in, const int* in_sizes, int n_in,
                              void* d_out, int out_size, void* d_ws, size_t ws_size,
                              hipStream_t stream) {
    const float* x = (const float*)d_in[0];
    const int* ei = (const int*)d_in[1];
    const float* W1l = (const float*)d_in[2];
    const float* b1 = (const float*)d_in[3];
    const float* W1r = (const float*)d_in[4];
    const float* W2l = (const float*)d_in[5];
    const float* b2 = (const float*)d_in[6];
    const float* W2r = (const float*)d_in[7];
    float* out = (float*)d_out;

    const int* src = ei;
    const int* dst = ei + N_EDGES_C;

    // int workspace region (first 8 MiB)
    int* iw = (int*)d_ws;
    int* bucket_counts = iw;                      // 1024
    int* bucket_base = iw + 1024;                 // NB+1 -> pad 1024
    int* cursor = iw + 2048;                      // 1024
    unsigned* edge_pkt = (unsigned*)(iw + 3072);  // 1.6M -> ends 1603072 ints
    u16* T1l = (u16*)(iw + 1603072);              // 4 x 32768 u16 = 256 KB
    u16* T1r = T1l + 32768;
    u16* T2l = T1r + 32768;
    u16* T2r = T2l + 32768;                       // ends ~6.7 MB < 8 MiB
    // bf16 region at byte offset 8 MiB; stride 12.85M u16 (pad for OOB tile reads)
    u16* ub = (u16*)((char*)d_ws + (8u << 20));
    u16* x_bf = ub;                               // [100000][128]
    u16* mean1 = ub + 12850000;                   // [100000][128]
    u16* p2 = ub + 25700000;                      // [100000][128]
    u16* outp = ub + 38550000;                    // [100000][128]

    hipMemsetAsync(bucket_counts, 0, 1024 * sizeof(int), stream);

    front_fused<<<CONV_BLOCKS + WB_BLOCKS + P1_BLOCKS, 256, 0, stream>>>(
        x, dst, W1l, W1r, W2l, W2r, x_bf, T1l, T1r, T2l, T2r, bucket_counts);
    bucket_scan<<<1, 1024, 0, stream>>>(bucket_counts, bucket_base, cursor);
    p2_scatter<<<(N_EDGES_C / 4 + 4095) / 4096, 1024, 0, stream>>>(src, dst, cursor,
                                                                   edge_pkt);

    // mean1 = mean_{src->node} x
    agg_bucket<false><<<NB, 512, 0, stream>>>(x_bf, bucket_base, edge_pkt, nullptr,
                                              mean1);
    // h = relu(mean1@W1l + x@W1r + b1);  p2 = h@W2l;  outp = h@W2r + b2
    fused_l1l2<<<(N_NODES_C + 63) / 64, 256, 0, stream>>>(
        mean1, x_bf, T1l, T1r, T2l, T2r, b1, b2, p2, outp, N_NODES_C);
    // out = mean_{src->node} p2 + outp   (fp32)
    agg_bucket<true><<<NB, 512, 0, stream>>>(p2, bucket_base, edge_pkt, outp, out);
}